// Round 14
// baseline (154.851 us; speedup 1.0000x reference)
//
#include <hip/hip_runtime.h>
#include <math.h>

#define IN_DIM 64
#define HH 4
#define CC 128   /* HH*DD */
#define NEG_SLOPE 0.1f

typedef __attribute__((ext_vector_type(8))) short short8;
typedef __attribute__((ext_vector_type(4))) float f32x4;

__device__ __forceinline__ float leaky(float v) { return v >= 0.f ? v : NEG_SLOPE * v; }

__device__ __forceinline__ unsigned f2bf(float f) {
  unsigned u = __float_as_uint(f);
  unsigned r = u + 0x7FFFu + ((u >> 16) & 1u);
  return r >> 16;
}

// ---- Kernel 1: fused {W swizzle + MFMA projection -> int8 feat + el/er} + bhist ----
// blocks [0, projB): projection. blocks [projB, projB+256): dst histogram.
__global__ __launch_bounds__(256) void k_projhist(
    const float* __restrict__ x, const float* __restrict__ W,
    const float* __restrict__ attn_l, const float* __restrict__ attn_r,
    unsigned char* __restrict__ featQ, float* __restrict__ scale,
    float* __restrict__ el, float* __restrict__ er,
    const int* __restrict__ dst, int* __restrict__ bcnt,
    int N, int E, int NB, int projB)
{
  __shared__ unsigned Wlds[4096];   // 16 KB swizzled Wt bf16
  __shared__ float Al[CC], Ar[CC];
  __shared__ int lh[512];
  int t = threadIdx.x;

  if ((int)blockIdx.x >= projB) {
    // ---------------- histogram branch ----------------
    int hb = blockIdx.x - projB;
    for (int i = t; i < NB; i += 256) lh[i] = 0;
    __syncthreads();
    for (int i = hb * 256 + t; i < E; i += 256 * 256)
      atomicAdd(&lh[dst[i] >> 8], 1);
    __syncthreads();
    for (int i = t; i < NB; i += 256) {
      int c = lh[i];
      if (c) atomicAdd(&bcnt[i], c);
    }
    return;
  }

  // ---------------- projection branch ----------------
#pragma unroll
  for (int i = 0; i < 16; ++i) {
    int idx = t + 256 * i;          // 0..4095
    int nn = idx >> 5, r = idx & 31;
    int bb = r >> 2, h2 = r & 3;
    int kk = bb * 8 + h2 * 2;
    unsigned lo = f2bf(W[kk * CC + nn]);
    unsigned hi = f2bf(W[(kk + 1) * CC + nn]);
    Wlds[nn * 32 + (bb ^ (nn & 7)) * 4 + h2] = lo | (hi << 16);
  }
  if (t < CC) { Al[t] = attn_l[t]; Ar[t] = attn_r[t]; }
  __syncthreads();

  int lane = t & 63;
  int l4 = lane >> 4, l16 = lane & 15;
  int node = blockIdx.x * 64 + (t >> 6) * 16 + l16;
  bool valid = node < N;
  int nrow = valid ? node : 0;

  short8 bfr[2];
#pragma unroll
  for (int s = 0; s < 2; ++s) {
    const float4* xp = (const float4*)&x[(size_t)nrow * 64 + s * 32 + l4 * 8];
    float4 xa = xp[0], xb = xp[1];
    union { short8 v; unsigned u[4]; } pk;
    pk.u[0] = f2bf(xa.x) | (f2bf(xa.y) << 16);
    pk.u[1] = f2bf(xa.z) | (f2bf(xa.w) << 16);
    pk.u[2] = f2bf(xb.x) | (f2bf(xb.y) << 16);
    pk.u[3] = f2bf(xb.z) | (f2bf(xb.w) << 16);
    bfr[s] = pk.v;
  }

  f32x4 acc[8];
#pragma unroll
  for (int c = 0; c < 8; ++c) acc[c] = (f32x4){0.f, 0.f, 0.f, 0.f};

#pragma unroll
  for (int c = 0; c < 8; ++c) {
    int n0 = c * 16 + l16;
    int sw = n0 & 7;
#pragma unroll
    for (int s = 0; s < 2; ++s) {
      int b = s * 4 + l4;
      union { short8 v; uint4 q; } af;
      af.q = *(const uint4*)&Wlds[n0 * 32 + (b ^ sw) * 4];
      acc[c] = __builtin_amdgcn_mfma_f32_16x16x32_bf16(af.v, bfr[s], acc[c], 0, 0, 0);
    }
  }

  float mx = 0.f;
#pragma unroll
  for (int c = 0; c < 8; ++c) {
#pragma unroll
    for (int r = 0; r < 4; ++r) mx = fmaxf(mx, fabsf(acc[c][r]));
  }
  mx = fmaxf(mx, __shfl_xor(mx, 16, 64));
  mx = fmaxf(mx, __shfl_xor(mx, 32, 64));
  float mxs = fmaxf(mx, 1e-20f);
  float inv = 127.f / mxs;

  if (valid) {
#pragma unroll
    for (int c = 0; c < 8; ++c) {
      int q0 = __float2int_rn(acc[c][0] * inv) + 128;
      int q1 = __float2int_rn(acc[c][1] * inv) + 128;
      int q2 = __float2int_rn(acc[c][2] * inv) + 128;
      int q3 = __float2int_rn(acc[c][3] * inv) + 128;
      unsigned u = (unsigned)(q0 & 0xff) | ((unsigned)(q1 & 0xff) << 8) |
                   ((unsigned)(q2 & 0xff) << 16) | ((unsigned)(q3 & 0xff) << 24);
      *(unsigned*)&featQ[(size_t)node * 128 + c * 16 + l4 * 4] = u;
    }
    if (l4 == 0) scale[node] = mxs * (1.f / 127.f);
  }

  float pl[4], pr[4];
#pragma unroll
  for (int h = 0; h < 4; ++h) {
    float sl = 0.f, sr = 0.f;
#pragma unroll
    for (int ct = 0; ct < 2; ++ct) {
      int c = 2 * h + ct;
      int cb = c * 16 + l4 * 4;
#pragma unroll
      for (int r = 0; r < 4; ++r) {
        sl = fmaf(acc[c][r], Al[cb + r], sl);
        sr = fmaf(acc[c][r], Ar[cb + r], sr);
      }
    }
    sl += __shfl_xor(sl, 16, 64); sl += __shfl_xor(sl, 32, 64);
    sr += __shfl_xor(sr, 16, 64); sr += __shfl_xor(sr, 32, 64);
    pl[h] = sl; pr[h] = sr;
  }
  if (l4 == 0 && valid) {
    *(float4*)&el[(size_t)node * 4] = make_float4(pl[0], pl[1], pl[2], pl[3]);
    *(float4*)&er[(size_t)node * 4] = make_float4(pr[0], pr[1], pr[2], pr[3]);
  }
}

// ---------------- counting-sort CSR build (bucket = dst >> 8) ----------------
__global__ __launch_bounds__(512) void k_bscan(const int* __restrict__ bcnt,
                                               int* __restrict__ gbase,
                                               int* __restrict__ gcursor, int NB) {
  __shared__ int sh[512];
  int t = threadIdx.x;
  int v = (t < NB) ? bcnt[t] : 0;
  sh[t] = v;
  __syncthreads();
  for (int off = 1; off < 512; off <<= 1) {
    int a = (t >= off) ? sh[t - off] : 0;
    __syncthreads();
    sh[t] += a;
    __syncthreads();
  }
  if (t < NB) {
    int e = sh[t] - v;
    gbase[t] = e;
    gcursor[t] = e;
  }
}

__global__ __launch_bounds__(512) void k_binA(const int* __restrict__ src,
                                              const int* __restrict__ dst,
                                              const float* __restrict__ w,
                                              int* __restrict__ gcursor,
                                              uint2* __restrict__ bkt, int E, int NB) {
  __shared__ int lh[512];
  __shared__ int lbase[512];
  int t = threadIdx.x;
  for (int i = t; i < NB; i += 512) lh[i] = 0;
  __syncthreads();
  long eb = (long)blockIdx.x * 8192;
  int b[16]; int r[16]; unsigned px[16]; unsigned pw[16];
#pragma unroll
  for (int i = 0; i < 16; ++i) {
    long e = eb + t + i * 512;
    bool v = e < E;
    int d = v ? dst[e] : 0;
    b[i] = d >> 8;
    px[i] = v ? ((unsigned)src[e] | ((unsigned)(d & 255) << 20)) : 0u;
    pw[i] = v ? ((const unsigned*)w)[e] : 0u;
    r[i] = v ? atomicAdd(&lh[b[i]], 1) : -1;
  }
  __syncthreads();
  for (int i = t; i < NB; i += 512) {
    int c = lh[i];
    lbase[i] = c ? atomicAdd(&gcursor[i], c) : 0;
  }
  __syncthreads();
#pragma unroll
  for (int i = 0; i < 16; ++i)
    if (r[i] >= 0) bkt[lbase[b[i]] + r[i]] = make_uint2(px[i], pw[i]);
}

__global__ __launch_bounds__(256) void k_binB(const uint2* __restrict__ bkt,
                                              const int* __restrict__ bcnt,
                                              const int* __restrict__ gbase,
                                              int* __restrict__ offs,
                                              int2* __restrict__ sp,
                                              int N, int E, int NB) {
  __shared__ int lh[256], sc[256], lcur[256];
  int b = blockIdx.x;
  int t = threadIdx.x;
  int base_b = gbase[b];
  int cnt_b = bcnt[b];
  lh[t] = 0;
  __syncthreads();
  for (int e = t; e < cnt_b; e += 256) {
    uint2 p = bkt[base_b + e];
    atomicAdd(&lh[(p.x >> 20) & 255], 1);
  }
  __syncthreads();
  int v = lh[t];
  sc[t] = v;
  __syncthreads();
  for (int off = 1; off < 256; off <<= 1) {
    int a = (t >= off) ? sc[t - off] : 0;
    __syncthreads();
    sc[t] += a;
    __syncthreads();
  }
  int excl = sc[t] - v;
  lcur[t] = excl;
  int n0 = b << 8;
  if (n0 + t < N) offs[n0 + t] = base_b + excl;
  if (b == NB - 1 && t == 0) offs[N] = E;
  __syncthreads();
  for (int e = t; e < cnt_b; e += 256) {
    uint2 p = bkt[base_b + e];
    int d = (p.x >> 20) & 255;
    int pos = atomicAdd(&lcur[d], 1);
    sp[base_b + pos] = make_int2((int)(p.x & 0xFFFFFu), (int)p.y);
  }
}

// ---------------- Kernel 3: persistent softmax + int8 gather (R11 body) ------------
__device__ __forceinline__ void fma16(float* acc, float& ka, float a, uint4 f) {
  ka += a;
  acc[0]  = fmaf(a, (float)( f.x        & 0xffu), acc[0]);
  acc[1]  = fmaf(a, (float)((f.x >> 8 ) & 0xffu), acc[1]);
  acc[2]  = fmaf(a, (float)((f.x >> 16) & 0xffu), acc[2]);
  acc[3]  = fmaf(a, (float)( f.x >> 24        ), acc[3]);
  acc[4]  = fmaf(a, (float)( f.y        & 0xffu), acc[4]);
  acc[5]  = fmaf(a, (float)((f.y >> 8 ) & 0xffu), acc[5]);
  acc[6]  = fmaf(a, (float)((f.y >> 16) & 0xffu), acc[6]);
  acc[7]  = fmaf(a, (float)( f.y >> 24        ), acc[7]);
  acc[8]  = fmaf(a, (float)( f.z        & 0xffu), acc[8]);
  acc[9]  = fmaf(a, (float)((f.z >> 8 ) & 0xffu), acc[9]);
  acc[10] = fmaf(a, (float)((f.z >> 16) & 0xffu), acc[10]);
  acc[11] = fmaf(a, (float)( f.z >> 24        ), acc[11]);
  acc[12] = fmaf(a, (float)( f.w        & 0xffu), acc[12]);
  acc[13] = fmaf(a, (float)((f.w >> 8 ) & 0xffu), acc[13]);
  acc[14] = fmaf(a, (float)((f.w >> 16) & 0xffu), acc[14]);
  acc[15] = fmaf(a, (float)( f.w >> 24        ), acc[15]);
}

__global__ __launch_bounds__(256) void k_aggregate(
    const int* __restrict__ offs, const int2* __restrict__ sp,
    const float* __restrict__ el, const float* __restrict__ er,
    const float* __restrict__ scale, const unsigned char* __restrict__ featQ,
    float* __restrict__ out, int ngroups, int N)
{
  __shared__ int    s_lds[4][64];   // fallback path only
  __shared__ float4 a_lds[4][64];   // per-edge alpha*scale (4 heads)

  int t = threadIdx.x;
  int lane = t & 63, wv = t >> 6;
  int half = lane >> 5, l32 = lane & 31;
  int grp = l32 >> 3;
  int c8 = l32 & 7;
  int hh = c8 >> 1;
  int hlane = lane & 32;
  const unsigned char* featl = featQ + c8 * 16;
  int* slf = &s_lds[wv][half * 32];
  const float* al = (const float*)&a_lds[wv][half * 32];

  for (int g = blockIdx.x; g < ngroups; g += gridDim.x) {
    int n = g * 8 + wv * 2 + half;
    if (n >= N) continue;

    int off0 = offs[n], off1 = offs[n + 1];
    int deg = off1 - off0;

    float acc[16];
#pragma unroll
    for (int i = 0; i < 16; ++i) acc[i] = 0.f;
    float ka = 0.f;

    if (deg > 0) {
      float4 erv = *reinterpret_cast<const float4*>(&er[(size_t)n * HH]);
      if (deg <= 32) {
        int dm1 = deg - 1;
        bool act = l32 < deg;
        int2 p = sp[off0 + (act ? l32 : 0)];
        int s = p.x;
        float wgt = __int_as_float(p.y);
        float sc = scale[s];

        // Phase A: issue gathers first
        uint4 fb[8];
#pragma unroll
        for (int k = 0; k < 4; ++k) {
          int ic = 4 * k + grp;
          int icc = ic < dm1 ? ic : dm1;
          int ss = __shfl(s, hlane + icc, 64);
          fb[k] = *reinterpret_cast<const uint4*>(featl + ((size_t)ss << 7));
        }
        if (deg > 16) {
#pragma unroll
          for (int k = 4; k < 8; ++k) {
            int ic = 4 * k + grp;
            int icc = ic < dm1 ? ic : dm1;
            int ss = __shfl(s, hlane + icc, 64);
            fb[k] = *reinterpret_cast<const uint4*>(featl + ((size_t)ss << 7));
          }
        }

        // Phase B: softmax (no max-sub) hides load latency
        float4 elv = *reinterpret_cast<const float4*>(&el[(size_t)s * HH]);
        float x0 = act ? __expf(leaky(elv.x + erv.x) * wgt) : 0.f;
        float x1 = act ? __expf(leaky(elv.y + erv.y) * wgt) : 0.f;
        float x2 = act ? __expf(leaky(elv.z + erv.z) * wgt) : 0.f;
        float x3 = act ? __expf(leaky(elv.w + erv.w) * wgt) : 0.f;
        float d0 = x0, d1 = x1, d2 = x2, d3 = x3;
#pragma unroll
        for (int d = 16; d >= 1; d >>= 1) {
          d0 += __shfl_xor(d0, d, 64);
          d1 += __shfl_xor(d1, d, 64);
          d2 += __shfl_xor(d2, d, 64);
          d3 += __shfl_xor(d3, d, 64);
        }
        float a0 = x0 * __builtin_amdgcn_rcpf(d0) * sc;
        float a1 = x1 * __builtin_amdgcn_rcpf(d1) * sc;
        float a2 = x2 * __builtin_amdgcn_rcpf(d2) * sc;
        float a3 = x3 * __builtin_amdgcn_rcpf(d3) * sc;
        a_lds[wv][half * 32 + l32] = make_float4(a0, a1, a2, a3);

        // Phase C: FMA
#pragma unroll
        for (int k = 0; k < 4; ++k) {
          int ic = 4 * k + grp;
          int icc = ic < dm1 ? ic : dm1;
          float a = (ic < deg) ? al[icc * 4 + hh] : 0.f;
          fma16(acc, ka, a, fb[k]);
        }
        if (deg > 16) {
#pragma unroll
          for (int k = 4; k < 8; ++k) {
            int ic = 4 * k + grp;
            int icc = ic < dm1 ? ic : dm1;
            float a = (ic < deg) ? al[icc * 4 + hh] : 0.f;
            fma16(acc, ka, a, fb[k]);
          }
        }
      } else {
        // chunked fallback (deg > 32): 3 passes over 32-edge chunks (rare)
        float m0 = -INFINITY, m1 = -INFINITY, m2 = -INFINITY, m3 = -INFINITY;
        for (int base = off0; base < off1; base += 32) {
          int j = base + l32;
          bool act = j < off1;
          int2 p = sp[act ? j : off0];
          float wgt = __int_as_float(p.y);
          float4 elv = *reinterpret_cast<const float4*>(&el[(size_t)p.x * HH]);
          float e0 = act ? leaky(elv.x + erv.x) * wgt : -INFINITY;
          float e1 = act ? leaky(elv.y + erv.y) * wgt : -INFINITY;
          float e2 = act ? leaky(elv.z + erv.z) * wgt : -INFINITY;
          float e3 = act ? leaky(elv.w + erv.w) * wgt : -INFINITY;
          m0 = fmaxf(m0, e0); m1 = fmaxf(m1, e1);
          m2 = fmaxf(m2, e2); m3 = fmaxf(m3, e3);
        }
#pragma unroll
        for (int d = 16; d >= 1; d >>= 1) {
          m0 = fmaxf(m0, __shfl_xor(m0, d, 64));
          m1 = fmaxf(m1, __shfl_xor(m1, d, 64));
          m2 = fmaxf(m2, __shfl_xor(m2, d, 64));
          m3 = fmaxf(m3, __shfl_xor(m3, d, 64));
        }
        float d0 = 0.f, d1 = 0.f, d2 = 0.f, d3 = 0.f;
        for (int base = off0; base < off1; base += 32) {
          int j = base + l32;
          bool act = j < off1;
          int2 p = sp[act ? j : off0];
          float wgt = __int_as_float(p.y);
          float4 elv = *reinterpret_cast<const float4*>(&el[(size_t)p.x * HH]);
          d0 += act ? __expf(leaky(elv.x + erv.x) * wgt - m0) : 0.f;
          d1 += act ? __expf(leaky(elv.y + erv.y) * wgt - m1) : 0.f;
          d2 += act ? __expf(leaky(elv.z + erv.z) * wgt - m2) : 0.f;
          d3 += act ? __expf(leaky(elv.w + erv.w) * wgt - m3) : 0.f;
        }
#pragma unroll
        for (int d = 16; d >= 1; d >>= 1) {
          d0 += __shfl_xor(d0, d, 64);
          d1 += __shfl_xor(d1, d, 64);
          d2 += __shfl_xor(d2, d, 64);
          d3 += __shfl_xor(d3, d, 64);
        }
        float i0 = __builtin_amdgcn_rcpf(d0), i1 = __builtin_amdgcn_rcpf(d1);
        float i2 = __builtin_amdgcn_rcpf(d2), i3 = __builtin_amdgcn_rcpf(d3);
        for (int base = off0; base < off1; base += 32) {
          int j = base + l32;
          bool act = j < off1;
          int2 p = sp[act ? j : off0];
          float wgt = __int_as_float(p.y);
          float sc = scale[p.x];
          float4 elv = *reinterpret_cast<const float4*>(&el[(size_t)p.x * HH]);
          float a0 = act ? __expf(leaky(elv.x + erv.x) * wgt - m0) * i0 * sc : 0.f;
          float a1 = act ? __expf(leaky(elv.y + erv.y) * wgt - m1) * i1 * sc : 0.f;
          float a2 = act ? __expf(leaky(elv.z + erv.z) * wgt - m2) * i2 * sc : 0.f;
          float a3 = act ? __expf(leaky(elv.w + erv.w) * wgt - m3) * i3 * sc : 0.f;
          slf[l32] = p.x << 7;
          a_lds[wv][half * 32 + l32] = make_float4(a0, a1, a2, a3);
          int cnt = off1 - base; if (cnt > 32) cnt = 32;
          int ne2 = (cnt + 3) >> 2;
          for (int b0 = 0; b0 < ne2; b0 += 4) {
            uint4 fb[4];
            float av[4];
#pragma unroll
            for (int k = 0; k < 4; ++k) {
              int idx = 4 * (b0 + k) + grp;
              bool vv = idx < cnt;
              int ic = vv ? idx : 0;
              av[k] = vv ? al[ic * 4 + hh] : 0.f;
              fb[k] = *reinterpret_cast<const uint4*>(featl + slf[ic]);
            }
#pragma unroll
            for (int k = 0; k < 4; ++k) fma16(acc, ka, av[k], fb[k]);
          }
        }
      }
    }
    // reduce across the 4 edge groups (lane bits 3,4 within the 32-lane half)
#pragma unroll
    for (int d = 8; d <= 16; d <<= 1) {
#pragma unroll
      for (int i = 0; i < 16; ++i) acc[i] += __shfl_xor(acc[i], d, 64);
      ka += __shfl_xor(ka, d, 64);
    }
    if (grp == 0) {
      float base = 128.f * ka;
      float* orow = &out[(size_t)n * CC + c8 * 16];
#pragma unroll
      for (int k = 0; k < 4; ++k) {
        f32x4 o = {acc[4 * k] - base, acc[4 * k + 1] - base,
                   acc[4 * k + 2] - base, acc[4 * k + 3] - base};
        __builtin_nontemporal_store(o, reinterpret_cast<f32x4*>(orow + 4 * k));
      }
    }
  }
}

// ---------------- launch ----------------
extern "C" void kernel_launch(void* const* d_in, const int* in_sizes, int n_in,
                              void* d_out, int out_size, void* d_ws, size_t ws_size,
                              hipStream_t stream)
{
  const float* x      = (const float*)d_in[1];
  const int*   src    = (const int*)d_in[2];
  const int*   dst    = (const int*)d_in[3];
  const float* w      = (const float*)d_in[4];
  const float* W_fc   = (const float*)d_in[5];
  const float* attn_l = (const float*)d_in[6];
  const float* attn_r = (const float*)d_in[7];
  float* out = (float*)d_out;

  int N = in_sizes[1] / IN_DIM;
  int E = in_sizes[2];
  int NB = (N + 255) / 256;   // nodes/bucket = 256; NB must be <= 512

  char* p = (char*)d_ws;
  auto alloc = [&](size_t bytes) {
    char* r = p;
    p += (bytes + 255) & ~size_t(255);
    return r;
  };
  unsigned char* featQ = (unsigned char*)alloc((size_t)N * 128);
  float* scale = (float*)alloc((size_t)N * 4);
  float* el    = (float*)alloc((size_t)N * HH * 4);
  float* er    = (float*)alloc((size_t)N * HH * 4);
  int*   offs  = (int*)alloc((size_t)(N + 1) * 4);
  int*   bcnt  = (int*)alloc(512 * 4);
  int*   gbase = (int*)alloc(512 * 4);
  int*   gcur  = (int*)alloc(512 * 4);
  uint2* bkt   = (uint2*)alloc((size_t)E * 8);
  int2*  sp    = (int2*)alloc((size_t)E * 8);

  hipMemsetAsync(bcnt, 0, 512 * 4, stream);

  int projB = (N + 63) / 64;
  k_projhist<<<projB + 256, 256, 0, stream>>>(x, W_fc, attn_l, attn_r,
                                              featQ, scale, el, er,
                                              dst, bcnt, N, E, NB, projB);
  k_bscan<<<1, 512, 0, stream>>>(bcnt, gbase, gcur, NB);
  k_binA<<<(E + 8191) / 8192, 512, 0, stream>>>(src, dst, w, gcur, bkt, E, NB);
  k_binB<<<NB, 256, 0, stream>>>(bkt, bcnt, gbase, offs, sp, N, E, NB);

  int ngroups = (N + 7) / 8;
  int agrid = ngroups < 2048 ? ngroups : 2048;
  k_aggregate<<<agrid, 256, 0, stream>>>(offs, sp, el, er, scale, featQ, out,
                                         ngroups, N);
}

// Round 16
// 133.741 us; speedup vs baseline: 1.1578x; 1.1578x over previous
//
#include <hip/hip_runtime.h>
#include <math.h>

#define IN_DIM 64
#define HH 4
#define CC 128   /* HH*DD */
#define NEG_SLOPE 0.1f

typedef __attribute__((ext_vector_type(8))) short short8;
typedef __attribute__((ext_vector_type(4))) float f32x4;

__device__ __forceinline__ float leaky(float v) { return v >= 0.f ? v : NEG_SLOPE * v; }

__device__ __forceinline__ unsigned f2bf(float f) {
  unsigned u = __float_as_uint(f);
  unsigned r = u + 0x7FFFu + ((u >> 16) & 1u);
  return r >> 16;
}

// ---------------- Kernel 0: build swizzled bf16 W^T image (128 rows x 32 u32) ------
__global__ void k_prepw(const float* __restrict__ W, unsigned* __restrict__ wt) {
  int tid = blockIdx.x * 256 + threadIdx.x;
  if (tid >= 128 * 32) return;
  int n = tid >> 5;
  int r = tid & 31;
  int b = r >> 2, h = r & 3;
  int k = b * 8 + h * 2;
  unsigned lo = f2bf(W[k * CC + n]);
  unsigned hi = f2bf(W[(k + 1) * CC + n]);
  wt[n * 32 + (b ^ (n & 7)) * 4 + h] = lo | (hi << 16);
}

// ---------------- Kernel 1: MFMA projection -> int8 feat (128B rows) + scale -------
__global__ __launch_bounds__(256) void k_project(
    const float* __restrict__ x, const unsigned* __restrict__ wt,
    const float* __restrict__ attn_l, const float* __restrict__ attn_r,
    unsigned char* __restrict__ featQ, float* __restrict__ scale,
    float* __restrict__ el, float* __restrict__ er, int N)
{
  __shared__ unsigned Wlds[4096];   // 16 KB swizzled Wt bf16
  __shared__ float Al[CC], Ar[CC];
  int t = threadIdx.x;
  {
    const uint4* s = (const uint4*)wt;
    uint4* d = (uint4*)Wlds;
#pragma unroll
    for (int i = 0; i < 4; ++i) d[t + 256 * i] = s[t + 256 * i];
  }
  if (t < CC) { Al[t] = attn_l[t]; Ar[t] = attn_r[t]; }
  __syncthreads();

  int lane = t & 63;
  int l4 = lane >> 4, l16 = lane & 15;
  int node = blockIdx.x * 64 + (t >> 6) * 16 + l16;
  bool valid = node < N;
  int nrow = valid ? node : 0;

  short8 bfr[2];
#pragma unroll
  for (int s = 0; s < 2; ++s) {
    const float4* xp = (const float4*)&x[(size_t)nrow * 64 + s * 32 + l4 * 8];
    float4 xa = xp[0], xb = xp[1];
    union { short8 v; unsigned u[4]; } pk;
    pk.u[0] = f2bf(xa.x) | (f2bf(xa.y) << 16);
    pk.u[1] = f2bf(xa.z) | (f2bf(xa.w) << 16);
    pk.u[2] = f2bf(xb.x) | (f2bf(xb.y) << 16);
    pk.u[3] = f2bf(xb.z) | (f2bf(xb.w) << 16);
    bfr[s] = pk.v;
  }

  f32x4 acc[8];
#pragma unroll
  for (int c = 0; c < 8; ++c) acc[c] = (f32x4){0.f, 0.f, 0.f, 0.f};

#pragma unroll
  for (int c = 0; c < 8; ++c) {
    int n0 = c * 16 + l16;
    int sw = n0 & 7;
#pragma unroll
    for (int s = 0; s < 2; ++s) {
      int b = s * 4 + l4;
      union { short8 v; uint4 q; } af;
      af.q = *(const uint4*)&Wlds[n0 * 32 + (b ^ sw) * 4];
      acc[c] = __builtin_amdgcn_mfma_f32_16x16x32_bf16(af.v, bfr[s], acc[c], 0, 0, 0);
    }
  }

  float mx = 0.f;
#pragma unroll
  for (int c = 0; c < 8; ++c) {
#pragma unroll
    for (int r = 0; r < 4; ++r) mx = fmaxf(mx, fabsf(acc[c][r]));
  }
  mx = fmaxf(mx, __shfl_xor(mx, 16, 64));
  mx = fmaxf(mx, __shfl_xor(mx, 32, 64));
  float mxs = fmaxf(mx, 1e-20f);
  float inv = 127.f / mxs;

  if (valid) {
#pragma unroll
    for (int c = 0; c < 8; ++c) {
      int q0 = __float2int_rn(acc[c][0] * inv) + 128;
      int q1 = __float2int_rn(acc[c][1] * inv) + 128;
      int q2 = __float2int_rn(acc[c][2] * inv) + 128;
      int q3 = __float2int_rn(acc[c][3] * inv) + 128;
      unsigned u = (unsigned)(q0 & 0xff) | ((unsigned)(q1 & 0xff) << 8) |
                   ((unsigned)(q2 & 0xff) << 16) | ((unsigned)(q3 & 0xff) << 24);
      *(unsigned*)&featQ[(size_t)node * 128 + c * 16 + l4 * 4] = u;
    }
    if (l4 == 0) scale[node] = mxs * (1.f / 127.f);
  }

  float pl[4], pr[4];
#pragma unroll
  for (int h = 0; h < 4; ++h) {
    float sl = 0.f, sr = 0.f;
#pragma unroll
    for (int ct = 0; ct < 2; ++ct) {
      int c = 2 * h + ct;
      int cb = c * 16 + l4 * 4;
#pragma unroll
      for (int r = 0; r < 4; ++r) {
        sl = fmaf(acc[c][r], Al[cb + r], sl);
        sr = fmaf(acc[c][r], Ar[cb + r], sr);
      }
    }
    sl += __shfl_xor(sl, 16, 64); sl += __shfl_xor(sl, 32, 64);
    sr += __shfl_xor(sr, 16, 64); sr += __shfl_xor(sr, 32, 64);
    pl[h] = sl; pr[h] = sr;
  }
  if (l4 == 0 && valid) {
    *(float4*)&el[(size_t)node * 4] = make_float4(pl[0], pl[1], pl[2], pl[3]);
    *(float4*)&er[(size_t)node * 4] = make_float4(pr[0], pr[1], pr[2], pr[3]);
  }
}

// ---------------- counting-sort CSR build (bucket = dst >> 8) ----------------
__global__ __launch_bounds__(256) void k_bhist(const int* __restrict__ dst,
                                               int* __restrict__ bcnt, int E, int NB) {
  __shared__ int lh[512];
  for (int i = threadIdx.x; i < NB; i += 256) lh[i] = 0;
  __syncthreads();
  int stride = gridDim.x * 256;
  for (int i = blockIdx.x * 256 + threadIdx.x; i < E; i += stride)
    atomicAdd(&lh[dst[i] >> 8], 1);
  __syncthreads();
  for (int i = threadIdx.x; i < NB; i += 256) {
    int c = lh[i];
    if (c) atomicAdd(&bcnt[i], c);
  }
}

__global__ __launch_bounds__(512) void k_bscan(const int* __restrict__ bcnt,
                                               int* __restrict__ gbase,
                                               int* __restrict__ gcursor, int NB) {
  __shared__ int sh[512];
  int t = threadIdx.x;
  int v = (t < NB) ? bcnt[t] : 0;
  sh[t] = v;
  __syncthreads();
  for (int off = 1; off < 512; off <<= 1) {
    int a = (t >= off) ? sh[t - off] : 0;
    __syncthreads();
    sh[t] += a;
    __syncthreads();
  }
  if (t < NB) {
    int e = sh[t] - v;
    gbase[t] = e;
    gcursor[t] = e;
  }
}

__global__ __launch_bounds__(512) void k_binA(const int* __restrict__ src,
                                              const int* __restrict__ dst,
                                              const float* __restrict__ w,
                                              int* __restrict__ gcursor,
                                              uint2* __restrict__ bkt, int E, int NB) {
  __shared__ int lh[512];
  __shared__ int lbase[512];
  int t = threadIdx.x;
  for (int i = t; i < NB; i += 512) lh[i] = 0;
  __syncthreads();
  long eb = (long)blockIdx.x * 8192;
  int b[16]; int r[16]; unsigned px[16]; unsigned pw[16];
#pragma unroll
  for (int i = 0; i < 16; ++i) {
    long e = eb + t + i * 512;
    bool v = e < E;
    int d = v ? dst[e] : 0;
    b[i] = d >> 8;
    px[i] = v ? ((unsigned)src[e] | ((unsigned)(d & 255) << 20)) : 0u;
    pw[i] = v ? ((const unsigned*)w)[e] : 0u;
    r[i] = v ? atomicAdd(&lh[b[i]], 1) : -1;
  }
  __syncthreads();
  for (int i = t; i < NB; i += 512) {
    int c = lh[i];
    lbase[i] = c ? atomicAdd(&gcursor[i], c) : 0;
  }
  __syncthreads();
#pragma unroll
  for (int i = 0; i < 16; ++i)
    if (r[i] >= 0) bkt[lbase[b[i]] + r[i]] = make_uint2(px[i], pw[i]);
}

__global__ __launch_bounds__(256) void k_binB(const uint2* __restrict__ bkt,
                                              const int* __restrict__ bcnt,
                                              const int* __restrict__ gbase,
                                              int* __restrict__ offs,
                                              int2* __restrict__ sp,
                                              int N, int E, int NB) {
  __shared__ int lh[256], sc[256], lcur[256];
  int b = blockIdx.x;
  int t = threadIdx.x;
  int base_b = gbase[b];
  int cnt_b = bcnt[b];
  lh[t] = 0;
  __syncthreads();
  for (int e = t; e < cnt_b; e += 256) {
    uint2 p = bkt[base_b + e];
    atomicAdd(&lh[(p.x >> 20) & 255], 1);
  }
  __syncthreads();
  int v = lh[t];
  sc[t] = v;
  __syncthreads();
  for (int off = 1; off < 256; off <<= 1) {
    int a = (t >= off) ? sc[t - off] : 0;
    __syncthreads();
    sc[t] += a;
    __syncthreads();
  }
  int excl = sc[t] - v;
  lcur[t] = excl;
  int n0 = b << 8;
  if (n0 + t < N) offs[n0 + t] = base_b + excl;
  if (b == NB - 1 && t == 0) offs[N] = E;
  __syncthreads();
  for (int e = t; e < cnt_b; e += 256) {
    uint2 p = bkt[base_b + e];
    int d = (p.x >> 20) & 255;
    int pos = atomicAdd(&lcur[d], 1);
    sp[base_b + pos] = make_int2((int)(p.x & 0xFFFFFu), (int)p.y);
  }
}

// ---------------- Kernel 3: fused softmax + int8 gather, 2 nodes/wave ----------
// half-wave per node; loads issued BEFORE softmax (latency hidden under VALU).
__device__ __forceinline__ void fma16(float* acc, float& ka, float a, uint4 f) {
  ka += a;
  acc[0]  = fmaf(a, (float)( f.x        & 0xffu), acc[0]);
  acc[1]  = fmaf(a, (float)((f.x >> 8 ) & 0xffu), acc[1]);
  acc[2]  = fmaf(a, (float)((f.x >> 16) & 0xffu), acc[2]);
  acc[3]  = fmaf(a, (float)( f.x >> 24        ), acc[3]);
  acc[4]  = fmaf(a, (float)( f.y        & 0xffu), acc[4]);
  acc[5]  = fmaf(a, (float)((f.y >> 8 ) & 0xffu), acc[5]);
  acc[6]  = fmaf(a, (float)((f.y >> 16) & 0xffu), acc[6]);
  acc[7]  = fmaf(a, (float)( f.y >> 24        ), acc[7]);
  acc[8]  = fmaf(a, (float)( f.z        & 0xffu), acc[8]);
  acc[9]  = fmaf(a, (float)((f.z >> 8 ) & 0xffu), acc[9]);
  acc[10] = fmaf(a, (float)((f.z >> 16) & 0xffu), acc[10]);
  acc[11] = fmaf(a, (float)( f.z >> 24        ), acc[11]);
  acc[12] = fmaf(a, (float)( f.w        & 0xffu), acc[12]);
  acc[13] = fmaf(a, (float)((f.w >> 8 ) & 0xffu), acc[13]);
  acc[14] = fmaf(a, (float)((f.w >> 16) & 0xffu), acc[14]);
  acc[15] = fmaf(a, (float)( f.w >> 24        ), acc[15]);
}

__global__ __launch_bounds__(256) void k_aggregate(
    const int* __restrict__ offs, const int2* __restrict__ sp,
    const float* __restrict__ el, const float* __restrict__ er,
    const float* __restrict__ scale, const unsigned char* __restrict__ featQ,
    float* __restrict__ out, int N)
{
  __shared__ int    s_lds[4][64];   // fallback path only
  __shared__ float4 a_lds[4][64];   // per-edge alpha*scale (4 heads)

  int t = threadIdx.x;
  int lane = t & 63, wv = t >> 6;
  int half = lane >> 5, l32 = lane & 31;
  int n = blockIdx.x * 8 + wv * 2 + half;
  if (n >= N) return;

  int off0 = offs[n], off1 = offs[n + 1];
  int deg = off1 - off0;
  int grp = l32 >> 3;            // edge slot within batch iter (0..3)
  int c8 = l32 & 7;              // 16-col group
  int hh = c8 >> 1;              // head owning these cols
  int hlane = lane & 32;         // base lane of my half
  const unsigned char* featl = featQ + c8 * 16;
  int* slf = &s_lds[wv][half * 32];
  const float* al = (const float*)&a_lds[wv][half * 32];

  float acc[16];
#pragma unroll
  for (int i = 0; i < 16; ++i) acc[i] = 0.f;
  float ka = 0.f;

  if (deg > 0) {
    float4 erv = *reinterpret_cast<const float4*>(&er[(size_t)n * HH]);
    if (deg <= 32) {
      int dm1 = deg - 1;
      bool act = l32 < deg;
      int2 p = sp[off0 + (act ? l32 : 0)];
      int s = p.x;
      float wgt = __int_as_float(p.y);
      float sc = scale[s];

      // ---- Phase A: issue gathers first (addresses = shfl'd src) ----
      uint4 fb[8];
#pragma unroll
      for (int k = 0; k < 4; ++k) {
        int ic = 4 * k + grp;
        int icc = ic < dm1 ? ic : dm1;
        int ss = __shfl(s, hlane + icc, 64);
        fb[k] = *reinterpret_cast<const uint4*>(featl + ((size_t)ss << 7));
      }
      if (deg > 16) {
#pragma unroll
        for (int k = 4; k < 8; ++k) {
          int ic = 4 * k + grp;
          int icc = ic < dm1 ? ic : dm1;
          int ss = __shfl(s, hlane + icc, 64);
          fb[k] = *reinterpret_cast<const uint4*>(featl + ((size_t)ss << 7));
        }
      }

      // ---- Phase B: softmax (no max-sub; |e| small) hides load latency ----
      float4 elv = *reinterpret_cast<const float4*>(&el[(size_t)s * HH]);
      float x0 = act ? __expf(leaky(elv.x + erv.x) * wgt) : 0.f;
      float x1 = act ? __expf(leaky(elv.y + erv.y) * wgt) : 0.f;
      float x2 = act ? __expf(leaky(elv.z + erv.z) * wgt) : 0.f;
      float x3 = act ? __expf(leaky(elv.w + erv.w) * wgt) : 0.f;
      float d0 = x0, d1 = x1, d2 = x2, d3 = x3;
#pragma unroll
      for (int d = 16; d >= 1; d >>= 1) {
        d0 += __shfl_xor(d0, d, 64);
        d1 += __shfl_xor(d1, d, 64);
        d2 += __shfl_xor(d2, d, 64);
        d3 += __shfl_xor(d3, d, 64);
      }
      float a0 = x0 * __builtin_amdgcn_rcpf(d0) * sc;
      float a1 = x1 * __builtin_amdgcn_rcpf(d1) * sc;
      float a2 = x2 * __builtin_amdgcn_rcpf(d2) * sc;
      float a3 = x3 * __builtin_amdgcn_rcpf(d3) * sc;
      a_lds[wv][half * 32 + l32] = make_float4(a0, a1, a2, a3);

      // ---- Phase C: FMA ----
#pragma unroll
      for (int k = 0; k < 4; ++k) {
        int ic = 4 * k + grp;
        int icc = ic < dm1 ? ic : dm1;
        float a = (ic < deg) ? al[icc * 4 + hh] : 0.f;
        fma16(acc, ka, a, fb[k]);
      }
      if (deg > 16) {
#pragma unroll
        for (int k = 4; k < 8; ++k) {
          int ic = 4 * k + grp;
          int icc = ic < dm1 ? ic : dm1;
          float a = (ic < deg) ? al[icc * 4 + hh] : 0.f;
          fma16(acc, ka, a, fb[k]);
        }
      }
    } else {
      // chunked (deg > 32): 3 passes over 32-edge chunks (rare)
      float m0 = -INFINITY, m1 = -INFINITY, m2 = -INFINITY, m3 = -INFINITY;
      for (int base = off0; base < off1; base += 32) {
        int j = base + l32;
        bool act = j < off1;
        int2 p = sp[act ? j : off0];
        float wgt = __int_as_float(p.y);
        float4 elv = *reinterpret_cast<const float4*>(&el[(size_t)p.x * HH]);
        float e0 = act ? leaky(elv.x + erv.x) * wgt : -INFINITY;
        float e1 = act ? leaky(elv.y + erv.y) * wgt : -INFINITY;
        float e2 = act ? leaky(elv.z + erv.z) * wgt : -INFINITY;
        float e3 = act ? leaky(elv.w + erv.w) * wgt : -INFINITY;
        m0 = fmaxf(m0, e0); m1 = fmaxf(m1, e1);
        m2 = fmaxf(m2, e2); m3 = fmaxf(m3, e3);
      }
#pragma unroll
      for (int d = 16; d >= 1; d >>= 1) {
        m0 = fmaxf(m0, __shfl_xor(m0, d, 64));
        m1 = fmaxf(m1, __shfl_xor(m1, d, 64));
        m2 = fmaxf(m2, __shfl_xor(m2, d, 64));
        m3 = fmaxf(m3, __shfl_xor(m3, d, 64));
      }
      float d0 = 0.f, d1 = 0.f, d2 = 0.f, d3 = 0.f;
      for (int base = off0; base < off1; base += 32) {
        int j = base + l32;
        bool act = j < off1;
        int2 p = sp[act ? j : off0];
        float wgt = __int_as_float(p.y);
        float4 elv = *reinterpret_cast<const float4*>(&el[(size_t)p.x * HH]);
        d0 += act ? __expf(leaky(elv.x + erv.x) * wgt - m0) : 0.f;
        d1 += act ? __expf(leaky(elv.y + erv.y) * wgt - m1) : 0.f;
        d2 += act ? __expf(leaky(elv.z + erv.z) * wgt - m2) : 0.f;
        d3 += act ? __expf(leaky(elv.w + erv.w) * wgt - m3) : 0.f;
      }
#pragma unroll
      for (int d = 16; d >= 1; d >>= 1) {
        d0 += __shfl_xor(d0, d, 64);
        d1 += __shfl_xor(d1, d, 64);
        d2 += __shfl_xor(d2, d, 64);
        d3 += __shfl_xor(d3, d, 64);
      }
      float i0 = __builtin_amdgcn_rcpf(d0), i1 = __builtin_amdgcn_rcpf(d1);
      float i2 = __builtin_amdgcn_rcpf(d2), i3 = __builtin_amdgcn_rcpf(d3);
      for (int base = off0; base < off1; base += 32) {
        int j = base + l32;
        bool act = j < off1;
        int2 p = sp[act ? j : off0];
        float wgt = __int_as_float(p.y);
        float sc = scale[p.x];
        float4 elv = *reinterpret_cast<const float4*>(&el[(size_t)p.x * HH]);
        float a0 = act ? __expf(leaky(elv.x + erv.x) * wgt - m0) * i0 * sc : 0.f;
        float a1 = act ? __expf(leaky(elv.y + erv.y) * wgt - m1) * i1 * sc : 0.f;
        float a2 = act ? __expf(leaky(elv.z + erv.z) * wgt - m2) * i2 * sc : 0.f;
        float a3 = act ? __expf(leaky(elv.w + erv.w) * wgt - m3) * i3 * sc : 0.f;
        slf[l32] = p.x << 7;
        a_lds[wv][half * 32 + l32] = make_float4(a0, a1, a2, a3);
        int cnt = off1 - base; if (cnt > 32) cnt = 32;
        int ne2 = (cnt + 3) >> 2;
        for (int b0 = 0; b0 < ne2; b0 += 4) {
          uint4 fb[4];
          float av[4];
#pragma unroll
          for (int k = 0; k < 4; ++k) {
            int idx = 4 * (b0 + k) + grp;
            bool vv = idx < cnt;
            int ic = vv ? idx : 0;
            av[k] = vv ? al[ic * 4 + hh] : 0.f;
            fb[k] = *reinterpret_cast<const uint4*>(featl + slf[ic]);
          }
#pragma unroll
          for (int k = 0; k < 4; ++k) fma16(acc, ka, av[k], fb[k]);
        }
      }
    }
  }
  // reduce across the 4 edge groups (lane bits 3,4 within the 32-lane half)
#pragma unroll
  for (int d = 8; d <= 16; d <<= 1) {
#pragma unroll
    for (int i = 0; i < 16; ++i) acc[i] += __shfl_xor(acc[i], d, 64);
    ka += __shfl_xor(ka, d, 64);
  }
  if (grp == 0) {
    float base = 128.f * ka;
    float* orow = &out[(size_t)n * CC + c8 * 16];
#pragma unroll
    for (int k = 0; k < 4; ++k) {
      f32x4 o = {acc[4 * k] - base, acc[4 * k + 1] - base,
                 acc[4 * k + 2] - base, acc[4 * k + 3] - base};
      *reinterpret_cast<f32x4*>(orow + 4 * k) = o;
    }
  }
}

// ---------------- launch ----------------
extern "C" void kernel_launch(void* const* d_in, const int* in_sizes, int n_in,
                              void* d_out, int out_size, void* d_ws, size_t ws_size,
                              hipStream_t stream)
{
  const float* x      = (const float*)d_in[1];
  const int*   src    = (const int*)d_in[2];
  const int*   dst    = (const int*)d_in[3];
  const float* w      = (const float*)d_in[4];
  const float* W_fc   = (const float*)d_in[5];
  const float* attn_l = (const float*)d_in[6];
  const float* attn_r = (const float*)d_in[7];
  float* out = (float*)d_out;

  int N = in_sizes[1] / IN_DIM;
  int E = in_sizes[2];
  int NB = (N + 255) / 256;   // nodes/bucket = 256; NB must be <= 512

  char* p = (char*)d_ws;
  auto alloc = [&](size_t bytes) {
    char* r = p;
    p += (bytes + 255) & ~size_t(255);
    return r;
  };
  unsigned char* featQ = (unsigned char*)alloc((size_t)N * 128);
  float* scale = (float*)alloc((size_t)N * 4);
  float* el    = (float*)alloc((size_t)N * HH * 4);
  float* er    = (float*)alloc((size_t)N * HH * 4);
  int*   offs  = (int*)alloc((size_t)(N + 1) * 4);
  int*   bcnt  = (int*)alloc(512 * 4);
  int*   gbase = (int*)alloc(512 * 4);
  int*   gcur  = (int*)alloc(512 * 4);
  unsigned* wtswz = (unsigned*)alloc(4096 * 4);
  uint2* bkt   = (uint2*)alloc((size_t)E * 8);
  int2*  sp    = (int2*)alloc((size_t)E * 8);

  hipMemsetAsync(bcnt, 0, 512 * 4, stream);

  k_prepw<<<16, 256, 0, stream>>>(W_fc, wtswz);
  k_project<<<(N + 63) / 64, 256, 0, stream>>>(x, wtswz, attn_l, attn_r,
                                               featQ, scale, el, er, N);
  k_bhist<<<256, 256, 0, stream>>>(dst, bcnt, E, NB);
  k_bscan<<<1, 512, 0, stream>>>(bcnt, gbase, gcur, NB);
  k_binA<<<(E + 8191) / 8192, 512, 0, stream>>>(src, dst, w, gcur, bkt, E, NB);
  k_binB<<<NB, 256, 0, stream>>>(bkt, bcnt, gbase, offs, sp, N, E, NB);
  k_aggregate<<<(N + 7) / 8, 256, 0, stream>>>(offs, sp, el, er, scale, featQ, out, N);
}